// Round 17
// baseline (299.443 us; speedup 1.0000x reference)
//
#include <hip/hip_runtime.h>
#include <stdint.h>

using short8 = __attribute__((ext_vector_type(8))) short;
using f32x4  = __attribute__((ext_vector_type(4))) float;
using f32x16 = __attribute__((ext_vector_type(16))) float;

#define L2E 1.44269504088896f

static __device__ __forceinline__ unsigned short f2bf(float f) {
  union { float f; uint32_t u; } v; v.f = f;
  uint32_t r = v.u + 0x7fffu + ((v.u >> 16) & 1u);
  return (unsigned short)(r >> 16);
}
static __device__ __forceinline__ float bf2f(unsigned short u) {
  union { uint32_t u; float f; } v; v.u = ((uint32_t)u) << 16;
  return v.f;
}

static __device__ __forceinline__ void gload16(const unsigned short* g, unsigned short* l) {
  __builtin_amdgcn_global_load_lds(
      (const __attribute__((address_space(1))) void*)g,
      (__attribute__((address_space(3))) void*)l, 16, 0, 0);
}

// ---- combined: weight transpose (blocks 0..1023) + GN partial sums (1024..1535)
__global__ __launch_bounds__(256) void prep_gn(
    const float* __restrict__ Wq, const float* __restrict__ Wk,
    const float* __restrict__ Wv, const float* __restrict__ Wo,
    const float* __restrict__ x,
    unsigned short* __restrict__ Wt, float* __restrict__ part) {
  int bid = blockIdx.x;
  int tid = threadIdx.x;
  if (bid < 1024) {
    int d = bid & 255, w = bid >> 8;
    const float* src = (w==0)?Wq:(w==1)?Wk:(w==2)?Wv:Wo;
    Wt[w*65536 + d*256 + tid] = f2bf(src[tid*256 + d]);
  } else {
    int v = bid - 1024;
    int ch = v & 63, b = v >> 6;
    float s = 0.f, q = 0.f;
    const float* p = x + ((b*4096) + ch*64)*256 + tid;
    for (int it = 0; it < 64; ++it) {
      float vv = p[it*256];
      s += vv; q += vv*vv;
    }
    s += __shfl_xor(s,1); q += __shfl_xor(q,1);
    s += __shfl_xor(s,2); q += __shfl_xor(q,2);
    s += __shfl_xor(s,4); q += __shfl_xor(q,4);
    if ((tid & 7) == 0) {
      int g = tid >> 3;
      part[((b*64 + ch)*32 + g)*2 + 0] = s;
      part[((b*64 + ch)*32 + g)*2 + 1] = q;
    }
  }
}

__global__ __launch_bounds__(256) void gn_apply(
    const float* __restrict__ x, const float* __restrict__ part,
    const float* __restrict__ sc, const float* __restrict__ bi,
    unsigned short* __restrict__ h) {
  int c = threadIdx.x, ch = blockIdx.x, b = blockIdx.y;
  int g = c >> 3;
  float s = 0.f, q = 0.f;
  for (int cc = 0; cc < 64; ++cc) {
    s += part[((b*64 + cc)*32 + g)*2 + 0];
    q += part[((b*64 + cc)*32 + g)*2 + 1];
  }
  float mean = s * (1.f/32768.f);
  float var  = q * (1.f/32768.f) - mean*mean;
  float rstd = rsqrtf(var + 1e-6f);
  float a  = rstd * sc[c];
  float d0 = bi[c] - mean * a;
  const float* p = x + ((b*4096) + ch*64)*256 + c;
  unsigned short* o = h + ((b*4096) + ch*64)*256 + c;
  for (int it = 0; it < 64; ++it)
    o[it*256] = f2bf(p[it*256] * a + d0);
}

// ---- combined Q+K projection (blocks 0..511) and V^T projection (512..1023)
__global__ __launch_bounds__(256) void gemm_qkvt(
    const unsigned short* __restrict__ A,      // h
    const unsigned short* __restrict__ Wt,     // 4x 256x256 transposed weights
    const float* __restrict__ bq,
    const float* __restrict__ bk,
    const float* __restrict__ bv,
    unsigned short* __restrict__ Qout,
    unsigned short* __restrict__ Kout,
    unsigned short* __restrict__ Vt) {
  int bid = blockIdx.x;
  int tid = threadIdx.x;
  int w = tid >> 6, l = tid & 63, lr = l & 15, lg = l >> 4;
  if (bid < 512) {
    const unsigned short* Wtq = Wt;
    const unsigned short* Wtk = Wt + 65536;
    int i0 = bid * 64;
    int j0 = w * 64;
    f32x4 accq[4][4] = {}, acck[4][4] = {};
#pragma unroll
    for (int kk = 0; kk < 8; ++kk) {
      short8 af[4], bfq[4], bfk[4];
#pragma unroll
      for (int mi = 0; mi < 4; ++mi)
        af[mi] = *(const short8*)(A + (i0 + mi*16 + lr)*256 + kk*32 + lg*8);
#pragma unroll
      for (int ni = 0; ni < 4; ++ni) {
        bfq[ni] = *(const short8*)(Wtq + (j0 + ni*16 + lr)*256 + kk*32 + lg*8);
        bfk[ni] = *(const short8*)(Wtk + (j0 + ni*16 + lr)*256 + kk*32 + lg*8);
      }
#pragma unroll
      for (int mi = 0; mi < 4; ++mi)
#pragma unroll
        for (int ni = 0; ni < 4; ++ni) {
          accq[mi][ni] = __builtin_amdgcn_mfma_f32_16x16x32_bf16(af[mi], bfq[ni], accq[mi][ni], 0,0,0);
          acck[mi][ni] = __builtin_amdgcn_mfma_f32_16x16x32_bf16(af[mi], bfk[ni], acck[mi][ni], 0,0,0);
        }
    }
#pragma unroll
    for (int mi = 0; mi < 4; ++mi) {
#pragma unroll
      for (int ni = 0; ni < 4; ++ni) {
        int j = j0 + ni*16 + lr;
#pragma unroll
        for (int r = 0; r < 4; ++r) {
          int i = i0 + mi*16 + lg*4 + r;
          Qout[i*256 + j] = f2bf((accq[mi][ni][r] + bq[j]) * 0.0625f);
          Kout[i*256 + j] = f2bf(acck[mi][ni][r] + bk[j]);
        }
      }
    }
  } else {
    const unsigned short* Wtv = Wt + 131072;
    int v = bid - 512;
    int i0 = (v & 3) * 64;                 // d rows
    int j0 = (v >> 2) * 256 + w * 64;      // m rows
    f32x4 acc[4][4] = {};
#pragma unroll
    for (int kk = 0; kk < 8; ++kk) {
      short8 af[4], bfr[4];
#pragma unroll
      for (int mi = 0; mi < 4; ++mi)
        af[mi] = *(const short8*)(Wtv + (i0 + mi*16 + lr)*256 + kk*32 + lg*8);
#pragma unroll
      for (int ni = 0; ni < 4; ++ni)
        bfr[ni] = *(const short8*)(A + (j0 + ni*16 + lr)*256 + kk*32 + lg*8);
#pragma unroll
      for (int mi = 0; mi < 4; ++mi)
#pragma unroll
        for (int ni = 0; ni < 4; ++ni)
          acc[mi][ni] = __builtin_amdgcn_mfma_f32_16x16x32_bf16(af[mi], bfr[ni], acc[mi][ni], 0,0,0);
    }
#pragma unroll
    for (int mi = 0; mi < 4; ++mi) {
#pragma unroll
      for (int ni = 0; ni < 4; ++ni) {
        int j = j0 + ni*16 + lr;
#pragma unroll
        for (int r = 0; r < 4; ++r) {
          int i = i0 + mi*16 + lg*4 + r;
          int idx = ((j >> 12) << 20) + i*4096 + (j & 4095);
          Vt[idx] = f2bf(acc[mi][ni][r] + bv[i]);
        }
      }
    }
  }
}

// ---- generic GEMM (fallback final projection): f32 out + bias + resid
__global__ __launch_bounds__(256) void gemm_bt(
    const unsigned short* __restrict__ A,
    const unsigned short* __restrict__ Bm,
    const float* __restrict__ bias_n,
    const float* __restrict__ resid,
    float* __restrict__ outp) {
  int tid = threadIdx.x;
  int w = tid >> 6, l = tid & 63, lr = l & 15, lg = l >> 4;
  int i0 = blockIdx.x * 64;
  int j0 = w * 64;
  f32x4 acc[4][4] = {};
#pragma unroll
  for (int kk = 0; kk < 8; ++kk) {
    short8 af[4], bfr[4];
#pragma unroll
    for (int mi = 0; mi < 4; ++mi)
      af[mi] = *(const short8*)(A + (i0 + mi*16 + lr)*256 + kk*32 + lg*8);
#pragma unroll
    for (int ni = 0; ni < 4; ++ni)
      bfr[ni] = *(const short8*)(Bm + (j0 + ni*16 + lr)*256 + kk*32 + lg*8);
#pragma unroll
    for (int mi = 0; mi < 4; ++mi)
#pragma unroll
      for (int ni = 0; ni < 4; ++ni)
        acc[mi][ni] = __builtin_amdgcn_mfma_f32_16x16x32_bf16(af[mi], bfr[ni], acc[mi][ni], 0,0,0);
  }
#pragma unroll
  for (int mi = 0; mi < 4; ++mi) {
#pragma unroll
    for (int ni = 0; ni < 4; ++ni) {
      int j = j0 + ni*16 + lr;
#pragma unroll
      for (int r = 0; r < 4; ++r) {
        int i = i0 + mi*16 + lg*4 + r;
        outp[i*256 + j] = acc[mi][ni][r] + bias_n[j] + resid[i*256 + j];
      }
    }
  }
}

// ---- fused merge + final projection: A = bf16(a1*P0 + a2*P1) built in-register
__global__ __launch_bounds__(256) void gemm_fin(
    const unsigned short* __restrict__ P0,
    const unsigned short* __restrict__ P1,
    const float* __restrict__ stats,
    const unsigned short* __restrict__ Bm,
    const float* __restrict__ bias_n,
    const float* __restrict__ resid,
    float* __restrict__ outp) {
  int tid = threadIdx.x;
  int w = tid >> 6, l = tid & 63, lr = l & 15, lg = l >> 4;
  int i0 = blockIdx.x * 64;
  int j0 = w * 64;
  float a1m[4], a2m[4];
#pragma unroll
  for (int mi = 0; mi < 4; ++mi) {
    int row = i0 + mi*16 + lr;
    float m1 = stats[row*2 + 0],           l1 = stats[row*2 + 1];
    float m2 = stats[65536 + row*2 + 0],   l2 = stats[65536 + row*2 + 1];
    float M  = fmaxf(m1, m2);
    float a1 = __builtin_amdgcn_exp2f((m1 - M) * L2E);
    float a2 = __builtin_amdgcn_exp2f((m2 - M) * L2E);
    float inv = 1.f / (a1*l1 + a2*l2);
    a1m[mi] = a1 * inv; a2m[mi] = a2 * inv;
  }
  f32x4 acc[4][4] = {};
#pragma unroll
  for (int kk = 0; kk < 8; ++kk) {
    short8 af[4], bfr[4];
#pragma unroll
    for (int mi = 0; mi < 4; ++mi) {
      int off = (i0 + mi*16 + lr)*256 + kk*32 + lg*8;
      short8 v1 = *(const short8*)(P0 + off);
      short8 v2 = *(const short8*)(P1 + off);
      union { unsigned int u[4]; short8 s8; } pk;
#pragma unroll
      for (int e = 0; e < 4; ++e) {
        float g0 = bf2f((unsigned short)v1[2*e])   * a1m[mi] + bf2f((unsigned short)v2[2*e])   * a2m[mi];
        float g1 = bf2f((unsigned short)v1[2*e+1]) * a1m[mi] + bf2f((unsigned short)v2[2*e+1]) * a2m[mi];
        asm("v_cvt_pk_bf16_f32 %0, %1, %2" : "=v"(pk.u[e]) : "v"(g0), "v"(g1));
      }
      af[mi] = pk.s8;
    }
#pragma unroll
    for (int ni = 0; ni < 4; ++ni)
      bfr[ni] = *(const short8*)(Bm + (j0 + ni*16 + lr)*256 + kk*32 + lg*8);
#pragma unroll
    for (int mi = 0; mi < 4; ++mi)
#pragma unroll
      for (int ni = 0; ni < 4; ++ni)
        acc[mi][ni] = __builtin_amdgcn_mfma_f32_16x16x32_bf16(af[mi], bfr[ni], acc[mi][ni], 0,0,0);
  }
#pragma unroll
  for (int mi = 0; mi < 4; ++mi) {
#pragma unroll
    for (int ni = 0; ni < 4; ++ni) {
      int j = j0 + ni*16 + lr;
#pragma unroll
      for (int r = 0; r < 4; ++r) {
        int i = i0 + mi*16 + lg*4 + r;
        outp[i*256 + j] = acc[mi][ni][r] + bias_n[j] + resid[i*256 + j];
      }
    }
  }
}

// ---- stage one KV step (K: 32x256, V: 256x32 of Vt half), XOR-swizzled source
// V swizzle: sg = s ^ ((d>>1)&3)  (matches 32x32 B-operand read; 8 groups/phase)
static __device__ __forceinline__ void stage_kv32(
    const unsigned short* __restrict__ Kb, const unsigned short* __restrict__ Vb,
    int kt, unsigned short* dK, unsigned short* dV, int w, int l) {
#pragma unroll
  for (int i = 0; i < 4; ++i) {
    int t = (w*4 + i)*64 + l;            // 16B-slot index, 0..1023
    int r = t >> 5, cs = t & 31;         // K: row r (512B = 32 slots)
    int cg = cs ^ (r & 7);
    gload16(Kb + (kt*32 + r)*256 + cg*8, dK + t*8);
  }
#pragma unroll
  for (int i = 0; i < 4; ++i) {
    int t = (w*4 + i)*64 + l;
    int d = t >> 2, s = t & 3;           // V: row d (64B = 4 slots)
    int sg = s ^ ((d >> 1) & 3);
    gload16(Vb + d*4096 + kt*32 + sg*8, dV + t*8);
  }
}

// ---- flash attention, key-split 2-way, 32x32x16 MFMA variant:
// grid 512: b=bid&7 (XCD pin), mt=(bid>>3)&31, ks=bid>>8 (key half).
// 4 waves x 32 Q-rows; KVBLK=32, dbuf LDS 64 KB -> 2 blocks/CU.
// Swapped QK (C=mfma(K,Q) -> S^T col=q=l&31); in-register softmax with a
// single shfl_xor(32); P-repack = 2 permlane32_swap per 16-key step.
__global__ __launch_bounds__(256, 2) void attn_fwd(
    const unsigned short* __restrict__ Q,
    const unsigned short* __restrict__ Kmat,
    const unsigned short* __restrict__ Vt,
    unsigned short* __restrict__ P0,
    unsigned short* __restrict__ P1,
    float* __restrict__ stats) {
  __shared__ __align__(16) unsigned short ldsK[2][32][256];   // 32 KB
  __shared__ __align__(16) unsigned short ldsV[2][256][32];   // 32 KB

  int tid = threadIdx.x;
  int w = tid >> 6, l = tid & 63, l31 = l & 31, hh = l >> 5;
  int b  = blockIdx.x & 7;
  int mt = (blockIdx.x >> 3) & 31;
  int ks = blockIdx.x >> 8;
  int m0 = mt*128 + w*32;
  int ksw = l31 & 7;                 // K row swizzle (row = l31)
  int vsw = (l31 >> 1) & 3;          // V row swizzle contribution (row=jt*32+l31)

  const unsigned short* Kb = Kmat + b*(4096*256) + ks*(2048*256);
  const unsigned short* Vb = Vt   + (b << 20) + ks*2048;
  unsigned short* Pp = ks ? P1 : P0;

  // Q fragments (MFMA B-operand: col = q = l31; k = hh*8+e per 16-wide step)
  short8 qf[16];
  {
    int qbase = ((b*4096) + m0 + l31)*256 + hh*8;
#pragma unroll
    for (int kk = 0; kk < 16; ++kk)
      qf[kk] = *(const short8*)(Q + qbase + kk*16);
  }

  float mrun = -1e30f, lrun = 0.f;
  f32x16 oacc[8] = {};

  stage_kv32(Kb, Vb, 0, &ldsK[0][0][0], &ldsV[0][0][0], w, l);

  for (int kt = 0; kt < 64; ++kt) {
    int cur = kt & 1;
    if (kt < 63) {
      stage_kv32(Kb, Vb, kt+1, &ldsK[cur^1][0][0], &ldsV[cur^1][0][0], w, l);
      asm volatile("s_waitcnt vmcnt(8)" ::: "memory");   // cur tile's 8 done
    } else {
      asm volatile("s_waitcnt vmcnt(0)" ::: "memory");
    }
    __builtin_amdgcn_s_barrier();
    __builtin_amdgcn_sched_barrier(0);

    const unsigned short (*Kc)[256] = ldsK[cur];
    const unsigned short (*Vc)[32]  = ldsV[cur];

    // S^T = K Q^T (32x32): col=q=l31; row key = (r&3)+8*(r>>2)+4*hh
    f32x16 s_ = {};
#pragma unroll
    for (int kk = 0; kk < 16; ++kk) {
      short8 kf = *(const short8*)&Kc[l31][(((kk << 1) | hh) ^ ksw)*8];
      s_ = __builtin_amdgcn_mfma_f32_32x32x16_bf16(kf, qf[kk], s_, 0,0,0);
    }

    // online softmax (full q-row: 16 in-lane + other half via shfl_xor 32)
    float x0 = fmaxf(fmaxf(s_[0],s_[1]),   fmaxf(s_[2],s_[3]));
    float x1 = fmaxf(fmaxf(s_[4],s_[5]),   fmaxf(s_[6],s_[7]));
    float x2 = fmaxf(fmaxf(s_[8],s_[9]),   fmaxf(s_[10],s_[11]));
    float x3 = fmaxf(fmaxf(s_[12],s_[13]), fmaxf(s_[14],s_[15]));
    float pmax = fmaxf(fmaxf(x0,x1), fmaxf(x2,x3));
    pmax = fmaxf(pmax, __shfl_xor(pmax, 32));
    if (__any(pmax > mrun + 8.f)) {          // rare rescale path
      float mnew = fmaxf(mrun, pmax);
      float alpha = __builtin_amdgcn_exp2f((mrun - mnew) * L2E);
      mrun = mnew;
      lrun *= alpha;
      float at[16];
#pragma unroll
      for (int r = 0; r < 16; ++r)
        at[r] = __shfl(alpha, (l & 32) | ((r&3) + 8*(r>>2) + 4*hh));
#pragma unroll
      for (int jt = 0; jt < 8; ++jt)
#pragma unroll
        for (int r = 0; r < 16; ++r) oacc[jt][r] *= at[r];
    }
    float mL = mrun * L2E;
    float p[16];
#pragma unroll
    for (int r = 0; r < 16; ++r)
      p[r] = __builtin_amdgcn_exp2f(s_[r]*L2E - mL);
    float t0 = ((p[0]+p[1]) + (p[2]+p[3])) + ((p[4]+p[5]) + (p[6]+p[7]));
    float t1 = ((p[8]+p[9]) + (p[10]+p[11])) + ((p[12]+p[13]) + (p[14]+p[15]));
    float sum = t0 + t1;
    lrun += sum + __shfl_xor(sum, 32);

    // repack P -> PV A-fragments, one per 16-key step.
    // D0=(p0,p1) D1=(p2,p3) D2=(p4,p5) D3=(p6,p7) (keys 4hh+.., 8+4hh+..);
    // permlane32_swap(a,b): a'=[a.lo|b.lo], b'=[a.hi|b.hi]  (r9-verified model)
    // => A-frag dwords [D0',D1',D2',D3'] hold keys 8hh+0..7. 
    short8 paf[2];
#pragma unroll
    for (int kk2 = 0; kk2 < 2; ++kk2) {
      int base = kk2*8;
      unsigned int D0, D1, D2, D3;
      asm("v_cvt_pk_bf16_f32 %0, %1, %2" : "=v"(D0) : "v"(p[base+0]), "v"(p[base+1]));
      asm("v_cvt_pk_bf16_f32 %0, %1, %2" : "=v"(D1) : "v"(p[base+2]), "v"(p[base+3]));
      asm("v_cvt_pk_bf16_f32 %0, %1, %2" : "=v"(D2) : "v"(p[base+4]), "v"(p[base+5]));
      asm("v_cvt_pk_bf16_f32 %0, %1, %2" : "=v"(D3) : "v"(p[base+6]), "v"(p[base+7]));
      asm("v_permlane32_swap_b32 %0, %1" : "+v"(D0), "+v"(D2));
      asm("v_permlane32_swap_b32 %0, %1" : "+v"(D1), "+v"(D3));
      union { unsigned int u[4]; short8 s8; } pk;
      pk.u[0] = D0; pk.u[1] = D1; pk.u[2] = D2; pk.u[3] = D3;
      paf[kk2] = pk.s8;
    }

    // O~ += P V : 8 d-tiles x 2 k-steps (B col = d = jt*32+l31)
#pragma unroll
    for (int kk2 = 0; kk2 < 2; ++kk2) {
#pragma unroll
      for (int jt = 0; jt < 8; ++jt) {
        short8 vf = *(const short8*)&Vc[jt*32 + l31][(((kk2 << 1) | hh) ^ vsw)*8];
        oacc[jt] = __builtin_amdgcn_mfma_f32_32x32x16_bf16(paf[kk2], vf, oacc[jt], 0,0,0);
      }
    }
    __builtin_amdgcn_sched_barrier(0);
    __builtin_amdgcn_s_barrier();
  }

  // epilogue: stats (m,l per q-row) + unnormalized O~
  if (l < 32) {
    int row = b*4096 + m0 + l;
    stats[(ks*32768 + row)*2 + 0] = mrun;
    stats[(ks*32768 + row)*2 + 1] = lrun;
  }
#pragma unroll
  for (int jt = 0; jt < 8; ++jt) {
#pragma unroll
    for (int r = 0; r < 16; ++r) {
      int q = (r&3) + 8*(r>>2) + 4*hh;
      Pp[((b*4096) + m0 + q)*256 + jt*32 + l31] = f2bf(oacc[jt][r]);
    }
  }
}

// ---- combine the two key-half partials (fallback path)
__global__ __launch_bounds__(256) void merge_attn(
    const unsigned short* __restrict__ P0,
    const unsigned short* __restrict__ P1,
    const float* __restrict__ stats,
    unsigned short* __restrict__ Out) {
  int tid = threadIdx.x;
  int row = blockIdx.x*8 + (tid >> 5);
  int c8  = (tid & 31) * 8;
  float m1 = stats[row*2 + 0],          l1 = stats[row*2 + 1];
  float m2 = stats[(32768 + row)*2 + 0], l2 = stats[(32768 + row)*2 + 1];
  float M  = fmaxf(m1, m2);
  float a1 = __builtin_amdgcn_exp2f((m1 - M) * L2E);
  float a2 = __builtin_amdgcn_exp2f((m2 - M) * L2E);
  float inv = 1.f / (a1*l1 + a2*l2);
  a1 *= inv; a2 *= inv;
  short8 v1 = *(const short8*)(P0 + row*256 + c8);
  short8 v2 = *(const short8*)(P1 + row*256 + c8);
  union { unsigned short u[8]; short8 s8; } o;
#pragma unroll
  for (int j = 0; j < 8; ++j)
    o.u[j] = f2bf(bf2f((unsigned short)v1[j])*a1 + bf2f((unsigned short)v2[j])*a2);
  *(short8*)(Out + row*256 + c8) = o.s8;
}

extern "C" void kernel_launch(void* const* d_in, const int* in_sizes, int n_in,
                              void* d_out, int out_size, void* d_ws, size_t ws_size,
                              hipStream_t stream) {
  (void)in_sizes; (void)n_in; (void)out_size;
  const float* x  = (const float*)d_in[0];
  const float* gs = (const float*)d_in[1];
  const float* gb = (const float*)d_in[2];
  const float* Wq = (const float*)d_in[3];
  const float* bq = (const float*)d_in[4];
  const float* Wk = (const float*)d_in[5];
  const float* bk = (const float*)d_in[6];
  const float* Wv = (const float*)d_in[7];
  const float* bv = (const float*)d_in[8];
  const float* Wo = (const float*)d_in[9];
  const float* bo = (const float*)d_in[10];

  char* ws = (char*)d_ws;
  unsigned short* h  = (unsigned short*)(ws);                       // 16 MB: GN out, then O~ part0
  unsigned short* Qb = (unsigned short*)(ws + (size_t)16777216);    // 16 MB
  unsigned short* Kb = (unsigned short*)(ws + (size_t)33554432);    // 16 MB
  unsigned short* Vt = (unsigned short*)(ws + (size_t)50331648);    // 16 MB  [b][d][n]
  unsigned short* Wt = (unsigned short*)(ws + (size_t)67108864);    // 512 KB (4x 256x256)
  float* part        = (float*)(ws + (size_t)67633152);             // 128 KB (GN partials)
  float* stats       = (float*)(ws + (size_t)67764224);             // 512 KB (m,l x2) ends 68288512
  unsigned short* P1ws = (unsigned short*)(ws + (size_t)68288512);  // 16 MB (only if ws allows)
  bool fuse = (ws_size >= (size_t)68288512 + 16777216);
  unsigned short* Op1 = fuse ? P1ws : (unsigned short*)d_out;

  prep_gn <<<dim3(1536), 256, 0, stream>>>(Wq, Wk, Wv, Wo, x, Wt, part);
  gn_apply<<<dim3(64,8),  256, 0, stream>>>(x, part, gs, gb, h);
  gemm_qkvt<<<dim3(1024), 256, 0, stream>>>(h, Wt, bq, bk, bv, Qb, Kb, Vt);
  attn_fwd<<<dim3(512),  256, 0, stream>>>(Qb, Kb, Vt, h, Op1, stats);   // P0 -> h
  if (fuse) {
    gemm_fin<<<dim3(512), 256, 0, stream>>>(h, P1ws, stats, Wt+196608, bo, x, (float*)d_out);
  } else {
    merge_attn<<<dim3(4096), 256, 0, stream>>>(h, Op1, stats, Qb);        // merged O -> Qb
    gemm_bt<<<dim3(512), 256, 0, stream>>>(Qb, Wt+196608, bo, x, (float*)d_out);
  }
}

// Round 18
// 293.161 us; speedup vs baseline: 1.0214x; 1.0214x over previous
//
#include <hip/hip_runtime.h>
#include <stdint.h>

using short8 = __attribute__((ext_vector_type(8))) short;
using f32x4  = __attribute__((ext_vector_type(4))) float;

#define L2E 1.44269504088896f

static __device__ __forceinline__ unsigned short f2bf(float f) {
  union { float f; uint32_t u; } v; v.f = f;
  uint32_t r = v.u + 0x7fffu + ((v.u >> 16) & 1u);
  return (unsigned short)(r >> 16);
}
static __device__ __forceinline__ float bf2f(unsigned short u) {
  union { uint32_t u; float f; } v; v.u = ((uint32_t)u) << 16;
  return v.f;
}

static __device__ __forceinline__ void gload16(const unsigned short* g, unsigned short* l) {
  __builtin_amdgcn_global_load_lds(
      (const __attribute__((address_space(1))) void*)g,
      (__attribute__((address_space(3))) void*)l, 16, 0, 0);
}

// cross-lane reductions over the four 16-lane groups (lanes ^16, ^32)
static __device__ __forceinline__ float red_add_lg(float x) {
  x += __shfl_xor(x, 16);
  x += __shfl_xor(x, 32);
  return x;
}
static __device__ __forceinline__ float red_max_lg(float x) {
  x = fmaxf(x, __shfl_xor(x, 16));
  x = fmaxf(x, __shfl_xor(x, 32));
  return x;
}

// ---- combined: weight transpose (blocks 0..1023) + GN partial sums (1024..1535)
__global__ __launch_bounds__(256) void prep_gn(
    const float* __restrict__ Wq, const float* __restrict__ Wk,
    const float* __restrict__ Wv, const float* __restrict__ Wo,
    const float* __restrict__ x,
    unsigned short* __restrict__ Wt, float* __restrict__ part) {
  int bid = blockIdx.x;
  int tid = threadIdx.x;
  if (bid < 1024) {
    int d = bid & 255, w = bid >> 8;
    const float* src = (w==0)?Wq:(w==1)?Wk:(w==2)?Wv:Wo;
    Wt[w*65536 + d*256 + tid] = f2bf(src[tid*256 + d]);
  } else {
    int v = bid - 1024;
    int ch = v & 63, b = v >> 6;
    float s = 0.f, q = 0.f;
    const float* p = x + ((b*4096) + ch*64)*256 + tid;
    for (int it = 0; it < 64; ++it) {
      float vv = p[it*256];
      s += vv; q += vv*vv;
    }
    s += __shfl_xor(s,1); q += __shfl_xor(q,1);
    s += __shfl_xor(s,2); q += __shfl_xor(q,2);
    s += __shfl_xor(s,4); q += __shfl_xor(q,4);
    if ((tid & 7) == 0) {
      int g = tid >> 3;
      part[((b*64 + ch)*32 + g)*2 + 0] = s;
      part[((b*64 + ch)*32 + g)*2 + 1] = q;
    }
  }
}

__global__ __launch_bounds__(256) void gn_apply(
    const float* __restrict__ x, const float* __restrict__ part,
    const float* __restrict__ sc, const float* __restrict__ bi,
    unsigned short* __restrict__ h) {
  int c = threadIdx.x, ch = blockIdx.x, b = blockIdx.y;
  int g = c >> 3;
  float s = 0.f, q = 0.f;
  for (int cc = 0; cc < 64; ++cc) {
    s += part[((b*64 + cc)*32 + g)*2 + 0];
    q += part[((b*64 + cc)*32 + g)*2 + 1];
  }
  float mean = s * (1.f/32768.f);
  float var  = q * (1.f/32768.f) - mean*mean;
  float rstd = rsqrtf(var + 1e-6f);
  float a  = rstd * sc[c];
  float d0 = bi[c] - mean * a;
  const float* p = x + ((b*4096) + ch*64)*256 + c;
  unsigned short* o = h + ((b*4096) + ch*64)*256 + c;
  for (int it = 0; it < 64; ++it)
    o[it*256] = f2bf(p[it*256] * a + d0);
}

// ---- combined Q+K projection (blocks 0..511) and V^T projection (512..1023)
// Both paths read h; fully independent, one dispatch.
__global__ __launch_bounds__(256) void gemm_qkvt(
    const unsigned short* __restrict__ A,      // h
    const unsigned short* __restrict__ Wt,     // 4x 256x256 transposed weights
    const float* __restrict__ bq,
    const float* __restrict__ bk,
    const float* __restrict__ bv,
    unsigned short* __restrict__ Qout,
    unsigned short* __restrict__ Kout,
    unsigned short* __restrict__ Vt) {
  int bid = blockIdx.x;
  int tid = threadIdx.x;
  int w = tid >> 6, l = tid & 63, lr = l & 15, lg = l >> 4;
  if (bid < 512) {
    // ---- Q+K path: A rows, two B matrices (A-fragments reused)
    const unsigned short* Wtq = Wt;
    const unsigned short* Wtk = Wt + 65536;
    int i0 = bid * 64;
    int j0 = w * 64;
    f32x4 accq[4][4] = {}, acck[4][4] = {};
#pragma unroll
    for (int kk = 0; kk < 8; ++kk) {
      short8 af[4], bfq[4], bfk[4];
#pragma unroll
      for (int mi = 0; mi < 4; ++mi)
        af[mi] = *(const short8*)(A + (i0 + mi*16 + lr)*256 + kk*32 + lg*8);
#pragma unroll
      for (int ni = 0; ni < 4; ++ni) {
        bfq[ni] = *(const short8*)(Wtq + (j0 + ni*16 + lr)*256 + kk*32 + lg*8);
        bfk[ni] = *(const short8*)(Wtk + (j0 + ni*16 + lr)*256 + kk*32 + lg*8);
      }
#pragma unroll
      for (int mi = 0; mi < 4; ++mi)
#pragma unroll
        for (int ni = 0; ni < 4; ++ni) {
          accq[mi][ni] = __builtin_amdgcn_mfma_f32_16x16x32_bf16(af[mi], bfq[ni], accq[mi][ni], 0,0,0);
          acck[mi][ni] = __builtin_amdgcn_mfma_f32_16x16x32_bf16(af[mi], bfk[ni], acck[mi][ni], 0,0,0);
        }
    }
#pragma unroll
    for (int mi = 0; mi < 4; ++mi) {
#pragma unroll
      for (int ni = 0; ni < 4; ++ni) {
        int j = j0 + ni*16 + lr;
#pragma unroll
        for (int r = 0; r < 4; ++r) {
          int i = i0 + mi*16 + lg*4 + r;
          Qout[i*256 + j] = f2bf((accq[mi][ni][r] + bq[j]) * 0.0625f);
          Kout[i*256 + j] = f2bf(acck[mi][ni][r] + bk[j]);
        }
      }
    }
  } else {
    // ---- V^T path: Vt[b][d][m] = (h Wv + bv)^T
    const unsigned short* Wtv = Wt + 131072;
    int v = bid - 512;
    int i0 = (v & 3) * 64;                 // d rows
    int j0 = (v >> 2) * 256 + w * 64;      // m rows
    f32x4 acc[4][4] = {};
#pragma unroll
    for (int kk = 0; kk < 8; ++kk) {
      short8 af[4], bfr[4];
#pragma unroll
      for (int mi = 0; mi < 4; ++mi)
        af[mi] = *(const short8*)(Wtv + (i0 + mi*16 + lr)*256 + kk*32 + lg*8);
#pragma unroll
      for (int ni = 0; ni < 4; ++ni)
        bfr[ni] = *(const short8*)(A + (j0 + ni*16 + lr)*256 + kk*32 + lg*8);
#pragma unroll
      for (int mi = 0; mi < 4; ++mi)
#pragma unroll
        for (int ni = 0; ni < 4; ++ni)
          acc[mi][ni] = __builtin_amdgcn_mfma_f32_16x16x32_bf16(af[mi], bfr[ni], acc[mi][ni], 0,0,0);
    }
#pragma unroll
    for (int mi = 0; mi < 4; ++mi) {
#pragma unroll
      for (int ni = 0; ni < 4; ++ni) {
        int j = j0 + ni*16 + lr;
#pragma unroll
        for (int r = 0; r < 4; ++r) {
          int i = i0 + mi*16 + lg*4 + r;
          int idx = ((j >> 12) << 20) + i*4096 + (j & 4095);
          Vt[idx] = f2bf(acc[mi][ni][r] + bv[i]);
        }
      }
    }
  }
}

// ---- generic GEMM (fallback final projection): f32 out + bias + resid
__global__ __launch_bounds__(256) void gemm_bt(
    const unsigned short* __restrict__ A,
    const unsigned short* __restrict__ Bm,
    const float* __restrict__ bias_n,
    const float* __restrict__ resid,
    float* __restrict__ outp) {
  int tid = threadIdx.x;
  int w = tid >> 6, l = tid & 63, lr = l & 15, lg = l >> 4;
  int i0 = blockIdx.x * 64;
  int j0 = w * 64;
  f32x4 acc[4][4] = {};
#pragma unroll
  for (int kk = 0; kk < 8; ++kk) {
    short8 af[4], bfr[4];
#pragma unroll
    for (int mi = 0; mi < 4; ++mi)
      af[mi] = *(const short8*)(A + (i0 + mi*16 + lr)*256 + kk*32 + lg*8);
#pragma unroll
    for (int ni = 0; ni < 4; ++ni)
      bfr[ni] = *(const short8*)(Bm + (j0 + ni*16 + lr)*256 + kk*32 + lg*8);
#pragma unroll
    for (int mi = 0; mi < 4; ++mi)
#pragma unroll
      for (int ni = 0; ni < 4; ++ni)
        acc[mi][ni] = __builtin_amdgcn_mfma_f32_16x16x32_bf16(af[mi], bfr[ni], acc[mi][ni], 0,0,0);
  }
#pragma unroll
  for (int mi = 0; mi < 4; ++mi) {
#pragma unroll
    for (int ni = 0; ni < 4; ++ni) {
      int j = j0 + ni*16 + lr;
#pragma unroll
      for (int r = 0; r < 4; ++r) {
        int i = i0 + mi*16 + lg*4 + r;
        outp[i*256 + j] = acc[mi][ni][r] + bias_n[j] + resid[i*256 + j];
      }
    }
  }
}

// ---- fused merge + final projection: A = bf16(a1*P0 + a2*P1) built in-register
__global__ __launch_bounds__(256) void gemm_fin(
    const unsigned short* __restrict__ P0,
    const unsigned short* __restrict__ P1,
    const float* __restrict__ stats,
    const unsigned short* __restrict__ Bm,
    const float* __restrict__ bias_n,
    const float* __restrict__ resid,
    float* __restrict__ outp) {
  int tid = threadIdx.x;
  int w = tid >> 6, l = tid & 63, lr = l & 15, lg = l >> 4;
  int i0 = blockIdx.x * 64;
  int j0 = w * 64;
  float a1m[4], a2m[4];
#pragma unroll
  for (int mi = 0; mi < 4; ++mi) {
    int row = i0 + mi*16 + lr;
    float m1 = stats[row*2 + 0],           l1 = stats[row*2 + 1];
    float m2 = stats[65536 + row*2 + 0],   l2 = stats[65536 + row*2 + 1];
    float M  = fmaxf(m1, m2);
    float a1 = __builtin_amdgcn_exp2f((m1 - M) * L2E);
    float a2 = __builtin_amdgcn_exp2f((m2 - M) * L2E);
    float inv = 1.f / (a1*l1 + a2*l2);
    a1m[mi] = a1 * inv; a2m[mi] = a2 * inv;
  }
  f32x4 acc[4][4] = {};
#pragma unroll
  for (int kk = 0; kk < 8; ++kk) {
    short8 af[4], bfr[4];
#pragma unroll
    for (int mi = 0; mi < 4; ++mi) {
      int off = (i0 + mi*16 + lr)*256 + kk*32 + lg*8;
      short8 v1 = *(const short8*)(P0 + off);
      short8 v2 = *(const short8*)(P1 + off);
      union { unsigned int u[4]; short8 s8; } pk;
#pragma unroll
      for (int e = 0; e < 4; ++e) {
        float g0 = bf2f((unsigned short)v1[2*e])   * a1m[mi] + bf2f((unsigned short)v2[2*e])   * a2m[mi];
        float g1 = bf2f((unsigned short)v1[2*e+1]) * a1m[mi] + bf2f((unsigned short)v2[2*e+1]) * a2m[mi];
        asm("v_cvt_pk_bf16_f32 %0, %1, %2" : "=v"(pk.u[e]) : "v"(g0), "v"(g1));
      }
      af[mi] = pk.s8;
    }
#pragma unroll
    for (int ni = 0; ni < 4; ++ni)
      bfr[ni] = *(const short8*)(Bm + (j0 + ni*16 + lr)*256 + kk*32 + lg*8);
#pragma unroll
    for (int mi = 0; mi < 4; ++mi)
#pragma unroll
      for (int ni = 0; ni < 4; ++ni)
        acc[mi][ni] = __builtin_amdgcn_mfma_f32_16x16x32_bf16(af[mi], bfr[ni], acc[mi][ni], 0,0,0);
  }
#pragma unroll
  for (int mi = 0; mi < 4; ++mi) {
#pragma unroll
    for (int ni = 0; ni < 4; ++ni) {
      int j = j0 + ni*16 + lr;
#pragma unroll
      for (int r = 0; r < 4; ++r) {
        int i = i0 + mi*16 + lg*4 + r;
        outp[i*256 + j] = acc[mi][ni][r] + bias_n[j] + resid[i*256 + j];
      }
    }
  }
}

// ---- stage one KV step (K: 32x256, V: 256x32 of Vt half), XOR-swizzled source
static __device__ __forceinline__ void stage_kv32(
    const unsigned short* __restrict__ Kb, const unsigned short* __restrict__ Vb,
    int kt, unsigned short* dK, unsigned short* dV, int w, int l) {
#pragma unroll
  for (int i = 0; i < 4; ++i) {
    int t = (w*4 + i)*64 + l;            // 16B-slot index, 0..1023
    int r = t >> 5, cs = t & 31;         // K: row r (512B = 32 slots)
    int cg = cs ^ (r & 7);
    gload16(Kb + (kt*32 + r)*256 + cg*8, dK + t*8);
  }
#pragma unroll
  for (int i = 0; i < 4; ++i) {
    int t = (w*4 + i)*64 + l;
    int d = t >> 2, s = t & 3;           // V: row d (64B = 4 slots)
    int sg = s ^ ((d ^ (d >> 2)) & 3);
    gload16(Vb + d*4096 + kt*32 + sg*8, dV + t*8);
  }
}

// ---- flash attention, key-split 2-way (flash-decoding):
// grid 512: b=bid&7 (XCD pin), mt=(bid>>3)&31, ks=bid>>8 (key half).
// 4 waves x 32 Q-rows; KVBLK=32, dbuf LDS 64 KB -> 2 blocks/CU (2 waves/SIMD).
// Writes UNNORMALIZED O~ (bf16) into Pp[ks] and (m,l) stats per row.
__global__ __launch_bounds__(256, 2) void attn_fwd(
    const unsigned short* __restrict__ Q,
    const unsigned short* __restrict__ Kmat,
    const unsigned short* __restrict__ Vt,
    unsigned short* __restrict__ P0,
    unsigned short* __restrict__ P1,
    float* __restrict__ stats) {
  __shared__ __align__(16) unsigned short ldsK[2][32][256];   // 32 KB
  __shared__ __align__(16) unsigned short ldsV[2][256][32];   // 32 KB

  int tid = threadIdx.x;
  int w = tid >> 6, l = tid & 63, lr = l & 15, lg = l >> 4;
  int b  = blockIdx.x & 7;
  int mt = (blockIdx.x >> 3) & 31;
  int ks = blockIdx.x >> 8;
  int m0 = mt*128 + w*32;
  int sw = lr & 7;
  int vsw = (lr ^ (lr >> 2)) & 3;        // V-read swizzle (matches stage side)
  int lgp = ((lg & 1) << 1) | (lg >> 1); // key-block map pi = {0,2,1,3}

  const unsigned short* Kb = Kmat + b*(4096*256) + ks*(2048*256);
  const unsigned short* Vb = Vt   + (b << 20) + ks*2048;
  unsigned short* Pp = ks ? P1 : P0;

  // Q fragments (MFMA B-operand: col = q = lr, elems = d)
  short8 qf[2][8];
#pragma unroll
  for (int qn = 0; qn < 2; ++qn) {
    int qbase = ((b*4096) + m0 + qn*16 + lr)*256 + lg*8;
#pragma unroll
    for (int kk = 0; kk < 8; ++kk)
      qf[qn][kk] = *(const short8*)(Q + qbase + kk*32);
  }

  float mrun[2], lrun[2];
  f32x4 oacc[2][16] = {};
  mrun[0] = mrun[1] = -1e30f;
  lrun[0] = lrun[1] = 0.f;

  stage_kv32(Kb, Vb, 0, &ldsK[0][0][0], &ldsV[0][0][0], w, l);

  for (int kt = 0; kt < 64; ++kt) {
    int cur = kt & 1;
    if (kt < 63) {
      stage_kv32(Kb, Vb, kt+1, &ldsK[cur^1][0][0], &ldsV[cur^1][0][0], w, l);
      asm volatile("s_waitcnt vmcnt(8)" ::: "memory");   // cur tile's 8 done
    } else {
      asm volatile("s_waitcnt vmcnt(0)" ::: "memory");
    }
    __builtin_amdgcn_s_barrier();
    __builtin_amdgcn_sched_barrier(0);

    const unsigned short (*Kc)[256] = ldsK[cur];
    const unsigned short (*Vc)[32]  = ldsV[cur];

    // S^T = K Q^T : s_[qn][kn][r] = S[key=kn*16+lg*4+r][q=qn*16+lr]
    f32x4 s_[2][2];
#pragma unroll
    for (int qn = 0; qn < 2; ++qn)
#pragma unroll
      for (int kn = 0; kn < 2; ++kn) s_[qn][kn] = (f32x4){0.f,0.f,0.f,0.f};
#pragma unroll
    for (int kn = 0; kn < 2; ++kn) {
#pragma unroll
      for (int kk = 0; kk < 8; ++kk) {
        short8 kf = *(const short8*)&Kc[kn*16 + lr][((kk*4 + lg) ^ sw)*8];
        s_[0][kn] = __builtin_amdgcn_mfma_f32_16x16x32_bf16(kf, qf[0][kk], s_[0][kn], 0,0,0);
        s_[1][kn] = __builtin_amdgcn_mfma_f32_16x16x32_bf16(kf, qf[1][kk], s_[1][kn], 0,0,0);
      }
    }

    // in-register online softmax + A-fragment repack, per qn
    short8 pa[2];
#pragma unroll
    for (int qn = 0; qn < 2; ++qn) {
      float ma = fmaxf(fmaxf(s_[qn][0][0], s_[qn][0][1]), fmaxf(s_[qn][0][2], s_[qn][0][3]));
      float mb = fmaxf(fmaxf(s_[qn][1][0], s_[qn][1][1]), fmaxf(s_[qn][1][2], s_[qn][1][3]));
      float pmax = fmaxf(ma, mb);
      if (__any(pmax > mrun[qn] + 8.f)) {          // rare rescale path
        float mx = red_max_lg(pmax);
        float mnew = fmaxf(mrun[qn], mx);
        float alpha = __builtin_amdgcn_exp2f((mrun[qn] - mnew) * L2E);
        mrun[qn] = mnew;
        lrun[qn] *= alpha;
        float at[4];
#pragma unroll
        for (int r = 0; r < 4; ++r) at[r] = __shfl(alpha, lg*4 + r);
#pragma unroll
        for (int jt = 0; jt < 16; ++jt)
#pragma unroll
          for (int r = 0; r < 4; ++r) oacc[qn][jt][r] *= at[r];
      }
      float mL = mrun[qn] * L2E;
      float p[2][4];
#pragma unroll
      for (int kn = 0; kn < 2; ++kn)
#pragma unroll
        for (int r = 0; r < 4; ++r)
          p[kn][r] = __builtin_amdgcn_exp2f(s_[qn][kn][r]*L2E - mL);
      float t0 = (p[0][0]+p[0][1]) + (p[0][2]+p[0][3]);
      float t1 = (p[1][0]+p[1][1]) + (p[1][2]+p[1][3]);
      lrun[qn] += red_add_lg(t0 + t1);
      // repack P -> PV A-fragment via permlane16_swap (verified r9):
      // lane group lg ends holding keys pi(lg)*8+0..7, pi={0,2,1,3};
      // the V-read compensates with slot lgp.
      unsigned int X0, X1, Y0, Y1;
      asm("v_cvt_pk_bf16_f32 %0, %1, %2" : "=v"(X0) : "v"(p[0][0]), "v"(p[0][1]));
      asm("v_cvt_pk_bf16_f32 %0, %1, %2" : "=v"(X1) : "v"(p[0][2]), "v"(p[0][3]));
      asm("v_cvt_pk_bf16_f32 %0, %1, %2" : "=v"(Y0) : "v"(p[1][0]), "v"(p[1][1]));
      asm("v_cvt_pk_bf16_f32 %0, %1, %2" : "=v"(Y1) : "v"(p[1][2]), "v"(p[1][3]));
      asm("v_permlane16_swap_b32 %0, %1" : "+v"(X0), "+v"(Y0));
      asm("v_permlane16_swap_b32 %0, %1" : "+v"(X1), "+v"(Y1));
      union { unsigned int u[4]; short8 s8; } pk;
      pk.u[0] = X0; pk.u[1] = X1; pk.u[2] = Y0; pk.u[3] = Y1;
      pa[qn] = pk.s8;
    }

    // O~ += P V : V-frag reused across qn; key-block lgp matches pi(lg)
#pragma unroll
    for (int jt = 0; jt < 16; ++jt) {
      short8 vf = *(const short8*)&Vc[jt*16 + lr][(lgp ^ vsw)*8];
      oacc[0][jt] = __builtin_amdgcn_mfma_f32_16x16x32_bf16(pa[0], vf, oacc[0][jt], 0,0,0);
      oacc[1][jt] = __builtin_amdgcn_mfma_f32_16x16x32_bf16(pa[1], vf, oacc[1][jt], 0,0,0);
    }
    __builtin_amdgcn_sched_barrier(0);
    __builtin_amdgcn_s_barrier();
  }

  // epilogue: store stats (m,l per q-row) and unnormalized O~
  if (lg == 0) {
#pragma unroll
    for (int qn = 0; qn < 2; ++qn) {
      int row = b*4096 + m0 + qn*16 + lr;
      stats[(ks*32768 + row)*2 + 0] = mrun[qn];
      stats[(ks*32768 + row)*2 + 1] = lrun[qn];
    }
  }
#pragma unroll
  for (int qn = 0; qn < 2; ++qn) {
#pragma unroll
    for (int r = 0; r < 4; ++r) {
      int row = ((b*4096) + m0 + qn*16 + lg*4 + r)*256;
#pragma unroll
      for (int jt = 0; jt < 16; ++jt)
        Pp[row + jt*16 + lr] = f2bf(oacc[qn][jt][r]);
    }
  }
}

// ---- combine the two key-half partials: O = (a1*O1 + a2*O2)/(a1*l1 + a2*l2)
__global__ __launch_bounds__(256) void merge_attn(
    const unsigned short* __restrict__ P0,
    const unsigned short* __restrict__ P1,
    const float* __restrict__ stats,
    unsigned short* __restrict__ Out) {
  int tid = threadIdx.x;
  int row = blockIdx.x*8 + (tid >> 5);
  int c8  = (tid & 31) * 8;
  float m1 = stats[row*2 + 0],          l1 = stats[row*2 + 1];
  float m2 = stats[(32768 + row)*2 + 0], l2 = stats[(32768 + row)*2 + 1];
  float M  = fmaxf(m1, m2);
  float a1 = __builtin_amdgcn_exp2f((m1 - M) * L2E);
  float a2 = __builtin_amdgcn_exp2f((m2 - M) * L2E);
  float inv = 1.f / (a1*l1 + a2*l2);
  a1 *= inv; a2 *= inv;
  short8 v1 = *(const short8*)(P0 + row*256 + c8);
  short8 v2 = *(const short8*)(P1 + row*256 + c8);
  union { unsigned short u[8]; short8 s8; } o;
#pragma unroll
  for (int j = 0; j < 8; ++j)
    o.u[j] = f2bf(bf2f((unsigned short)v1[j])*a1 + bf2f((unsigned short)v2[j])*a2);
  *(short8*)(Out + row*256 + c8) = o.s8;
}

extern "C" void kernel_launch(void* const* d_in, const int* in_sizes, int n_in,
                              void* d_out, int out_size, void* d_ws, size_t ws_size,
                              hipStream_t stream) {
  (void)in_sizes; (void)n_in; (void)out_size;
  const float* x  = (const float*)d_in[0];
  const float* gs = (const float*)d_in[1];
  const float* gb = (const float*)d_in[2];
  const float* Wq = (const float*)d_in[3];
  const float* bq = (const float*)d_in[4];
  const float* Wk = (const float*)d_in[5];
  const float* bk = (const float*)d_in[6];
  const float* Wv = (const float*)d_in[7];
  const float* bv = (const float*)d_in[8];
  const float* Wo = (const float*)d_in[9];
  const float* bo = (const float*)d_in[10];

  char* ws = (char*)d_ws;
  unsigned short* h  = (unsigned short*)(ws);                       // 16 MB: GN out, then O~ part0
  unsigned short* Qb = (unsigned short*)(ws + (size_t)16777216);    // 16 MB
  unsigned short* Kb = (unsigned short*)(ws + (size_t)33554432);    // 16 MB
  unsigned short* Vt = (unsigned short*)(ws + (size_t)50331648);    // 16 MB  [b][d][n]
  unsigned short* Wt = (unsigned short*)(ws + (size_t)67108864);    // 512 KB (4x 256x256)
  float* part        = (float*)(ws + (size_t)67633152);             // 128 KB (GN partials)
  float* stats       = (float*)(ws + (size_t)67764224);             // 512 KB (m,l x2) ends 68288512
  unsigned short* P1ws = (unsigned short*)(ws + (size_t)68288512);  // 16 MB (only if ws allows)
  bool fuse = (ws_size >= (size_t)68288512 + 16777216);
  unsigned short* Op1 = fuse ? P1ws : (unsigned short*)d_out;

  prep_gn <<<dim3(1536), 256, 0, stream>>>(Wq, Wk, Wv, Wo, x, Wt, part);
  gn_apply<<<dim3(64,8),  256, 0, stream>>>(x, part, gs, gb, h);
  gemm_qkvt<<<dim3(1024), 256, 0, stream>>>(h, Wt, bq, bk, bv, Qb, Kb, Vt);
  attn_fwd<<<dim3(512),  256, 0, stream>>>(Qb, Kb, Vt, h, Op1, stats);   // P0 -> h
  if (fuse) {
    gemm_fin<<<dim3(512), 256, 0, stream>>>(h, P1ws, stats, Wt+196608, bo, x, (float*)d_out);
  } else {
    merge_attn<<<dim3(4096), 256, 0, stream>>>(h, Op1, stats, Qb);        // merged O -> Qb
    gemm_bt<<<dim3(512), 256, 0, stream>>>(Qb, Wt+196608, bo, x, (float*)d_out);
  }
}